// Round 1
// baseline (419.176 us; speedup 1.0000x reference)
//
#include <hip/hip_runtime.h>
#include <hip/hip_bf16.h>

#define M_DIM 8192
#define K_DIM 2048
#define N_DIM 4096
#define NGROUP 32
#define EPSV 1e-5f

typedef __bf16 bf16x8 __attribute__((ext_vector_type(8)));
typedef __bf16 bf16x4 __attribute__((ext_vector_type(4)));
typedef float floatx4 __attribute__((ext_vector_type(4)));

__device__ __forceinline__ void g2lds16(const void* g, void* l) {
    __builtin_amdgcn_global_load_lds(
        (__attribute__((address_space(1))) void*)(uintptr_t)g,
        (__attribute__((address_space(3))) void*)(uint32_t)(uintptr_t)l,
        16, 0, 0);
}

// ---------------- kernel 1: fp32 -> bf16 cast of x and W ----------------
__global__ __launch_bounds__(256) void convert_bf16(
    const float* __restrict__ x, const float* __restrict__ w,
    __bf16* __restrict__ xb, __bf16* __restrict__ wb)
{
    const size_t nx = (size_t)M_DIM * K_DIM / 4;
    const size_t nw = (size_t)N_DIM * K_DIM / 4;
    size_t i = (size_t)blockIdx.x * 256 + threadIdx.x;
    if (i < nx) {
        float4 v = ((const float4*)x)[i];
        bf16x4 o = { (__bf16)v.x, (__bf16)v.y, (__bf16)v.z, (__bf16)v.w };
        ((bf16x4*)xb)[i] = o;
    } else if (i < nx + nw) {
        size_t j = i - nx;
        float4 v = ((const float4*)w)[j];
        bf16x4 o = { (__bf16)v.x, (__bf16)v.y, (__bf16)v.z, (__bf16)v.w };
        ((bf16x4*)wb)[j] = o;
    }
}

// ---- kernel 2: bf16 MFMA GEMM (y = x*W^T + b) fused with GroupNorm + group-min ----
// Tile: BM=128, BN=128, BK=64. 256 threads = 4 waves, wave w owns rows
// [w*32, w*32+32) x all 128 cols. BN == group size (128) and tiles are
// group-aligned, so mean/var/min over the group are exact in-block.
__global__ __launch_bounds__(256) void gemm_gn_min(
    const __bf16* __restrict__ xb, const __bf16* __restrict__ wb,
    const float* __restrict__ bg, const float* __restrict__ gamma,
    const float* __restrict__ beta, float* __restrict__ gmin)
{
    __shared__ __bf16 lA[128 * 64];   // 16 KiB
    __shared__ __bf16 lB[128 * 64];   // 16 KiB

    const int t = threadIdx.x;
    const int m0 = blockIdx.x * 128;
    const int n0 = blockIdx.y * 128;
    const int w = t >> 6;        // wave 0..3
    const int l = t & 63;
    const int quad = l >> 4;
    const int r = l & 15;

    // staging: thread t loads 16B at LDS byte offset t*16 (+ j*4096 per issue)
    const int rowS = t >> 3;          // 0..31
    const int colS = (t & 7) * 8;     // element col in 64-wide K-slab

    const __bf16* gA = xb + (size_t)(m0 + rowS) * K_DIM + colS;
    const __bf16* gB = wb + (size_t)(n0 + rowS) * K_DIM + colS;
    __bf16* sA = &lA[rowS * 64 + colS];
    __bf16* sB = &lB[rowS * 64 + colS];

    floatx4 acc[2][8];
    #pragma unroll
    for (int i = 0; i < 2; ++i)
        #pragma unroll
        for (int j = 0; j < 8; ++j)
            acc[i][j] = (floatx4){0.f, 0.f, 0.f, 0.f};

    for (int k0 = 0; k0 < K_DIM; k0 += 64) {
        __syncthreads();
        #pragma unroll
        for (int j = 0; j < 4; ++j) {
            g2lds16(gA + k0 + (size_t)(j * 32) * K_DIM, sA + j * 32 * 64);
            g2lds16(gB + k0 + (size_t)(j * 32) * K_DIM, sB + j * 32 * 64);
        }
        __syncthreads();   // drains vmcnt for global_load_lds
        #pragma unroll
        for (int ks = 0; ks < 2; ++ks) {
            bf16x8 af[2], bfv[8];
            #pragma unroll
            for (int mt = 0; mt < 2; ++mt)
                af[mt] = *(const bf16x8*)&lA[(w * 32 + mt * 16 + r) * 64 + ks * 32 + quad * 8];
            #pragma unroll
            for (int nt = 0; nt < 8; ++nt)
                bfv[nt] = *(const bf16x8*)&lB[(nt * 16 + r) * 64 + ks * 32 + quad * 8];
            #pragma unroll
            for (int mt = 0; mt < 2; ++mt)
                #pragma unroll
                for (int nt = 0; nt < 8; ++nt)
                    acc[mt][nt] = __builtin_amdgcn_mfma_f32_16x16x32_bf16(
                        af[mt], bfv[nt], acc[mt][nt], 0, 0, 0);
        }
    }

    // ---- epilogue: + b_gemm, GroupNorm stats over the 128-col group, min ----
    // C/D layout (verified m89/m91): col = lane&15, row = (lane>>4)*4 + reg.
    float bgv[8], gv[8], bv[8];
    #pragma unroll
    for (int nt = 0; nt < 8; ++nt) {
        int c = n0 + nt * 16 + r;
        bgv[nt] = bg[c];
        gv[nt]  = gamma[c];
        bv[nt]  = beta[c];
    }

    #pragma unroll
    for (int mt = 0; mt < 2; ++mt) {
        #pragma unroll
        for (int reg = 0; reg < 4; ++reg) {
            float yv[8];
            float s = 0.f, ss = 0.f;
            #pragma unroll
            for (int nt = 0; nt < 8; ++nt) {
                float y = acc[mt][nt][reg] + bgv[nt];
                yv[nt] = y;
                s += y;
                ss += y * y;
            }
            // reduce across the 16 lanes of this quad (cols nt*16+r cover all 128)
            #pragma unroll
            for (int d = 1; d < 16; d <<= 1) {
                s  += __shfl_xor(s,  d, 64);
                ss += __shfl_xor(ss, d, 64);
            }
            float mean = s * (1.0f / 128.0f);
            float var  = ss * (1.0f / 128.0f) - mean * mean;
            float rstd = rsqrtf(var + EPSV);
            float mn = 1e30f;
            #pragma unroll
            for (int nt = 0; nt < 8; ++nt) {
                float z = (yv[nt] - mean) * rstd * gv[nt] + bv[nt];
                mn = fminf(mn, z);
            }
            #pragma unroll
            for (int d = 1; d < 16; d <<= 1)
                mn = fminf(mn, __shfl_xor(mn, d, 64));
            if (r == 0) {
                int R = m0 + w * 32 + mt * 16 + quad * 4 + reg;
                gmin[(size_t)R * NGROUP + blockIdx.y] = mn;
            }
        }
    }
}

// ---------------- kernel 3: rowmin over groups + broadcast bias ----------------
__global__ __launch_bounds__(256) void finalize(
    const float* __restrict__ gmin, const float* __restrict__ bias,
    float* __restrict__ out)
{
    const int m = blockIdx.x;
    const int t = threadIdx.x;
    float v = gmin[(size_t)m * NGROUP + (t & 31)];
    #pragma unroll
    for (int d = 1; d < 32; d <<= 1)
        v = fminf(v, __shfl_xor(v, d, 64));
    float4* out4 = (float4*)(out + (size_t)m * N_DIM);
    const float4* bias4 = (const float4*)bias;
    for (int i = t; i < N_DIM / 4; i += 256) {
        float4 b = bias4[i];
        out4[i] = make_float4(v + b.x, v + b.y, v + b.z, v + b.w);
    }
}

extern "C" void kernel_launch(void* const* d_in, const int* in_sizes, int n_in,
                              void* d_out, int out_size, void* d_ws, size_t ws_size,
                              hipStream_t stream)
{
    const float* x     = (const float*)d_in[0];
    const float* W     = (const float*)d_in[1];
    const float* bg    = (const float*)d_in[2];
    const float* gamma = (const float*)d_in[3];
    const float* beta  = (const float*)d_in[4];
    const float* bias  = (const float*)d_in[5];
    float* out = (float*)d_out;

    // ws layout: xb (32 MiB bf16) | wb (16 MiB bf16) | gmin (1 MiB fp32) = 49 MiB
    __bf16* xb = (__bf16*)d_ws;
    __bf16* wb = xb + (size_t)M_DIM * K_DIM;
    float* gmin = (float*)(wb + (size_t)N_DIM * K_DIM);

    size_t ntot4 = ((size_t)M_DIM * K_DIM + (size_t)N_DIM * K_DIM) / 4;
    int cvt_blocks = (int)((ntot4 + 255) / 256);
    convert_bf16<<<cvt_blocks, 256, 0, stream>>>(x, W, xb, wb);

    dim3 grid(M_DIM / 128, N_DIM / 128);
    gemm_gn_min<<<grid, 256, 0, stream>>>(xb, wb, bg, gamma, beta, gmin);

    finalize<<<M_DIM, 256, 0, stream>>>(gmin, bias, out);
}

// Round 2
// 388.997 us; speedup vs baseline: 1.0776x; 1.0776x over previous
//
#include <hip/hip_runtime.h>
#include <hip/hip_bf16.h>

#define M_DIM 8192
#define K_DIM 2048
#define N_DIM 4096
#define NGROUP 32
#define EPSV 1e-5f

typedef __bf16 bf16x8 __attribute__((ext_vector_type(8)));
typedef __bf16 bf16x4 __attribute__((ext_vector_type(4)));
typedef float floatx4 __attribute__((ext_vector_type(4)));

__device__ __forceinline__ void g2lds16(const void* g, void* l) {
    __builtin_amdgcn_global_load_lds(
        (__attribute__((address_space(1))) void*)(uintptr_t)g,
        (__attribute__((address_space(3))) void*)(uint32_t)(uintptr_t)l,
        16, 0, 0);
}

// ---------------- kernel 1: fp32 -> bf16 cast of x and W ----------------
__global__ __launch_bounds__(256) void convert_bf16(
    const float* __restrict__ x, const float* __restrict__ w,
    __bf16* __restrict__ xb, __bf16* __restrict__ wb)
{
    const size_t nx = (size_t)M_DIM * K_DIM / 4;
    const size_t nw = (size_t)N_DIM * K_DIM / 4;
    size_t i = (size_t)blockIdx.x * 256 + threadIdx.x;
    if (i < nx) {
        float4 v = ((const float4*)x)[i];
        bf16x4 o = { (__bf16)v.x, (__bf16)v.y, (__bf16)v.z, (__bf16)v.w };
        ((bf16x4*)xb)[i] = o;
    } else if (i < nx + nw) {
        size_t j = i - nx;
        float4 v = ((const float4*)w)[j];
        bf16x4 o = { (__bf16)v.x, (__bf16)v.y, (__bf16)v.z, (__bf16)v.w };
        ((bf16x4*)wb)[j] = o;
    }
}

// ---- kernel 2: bf16 MFMA GEMM (y = x*W^T + b) fused with GroupNorm + group-min ----
// Tile: BM=128, BN=128, BK=64. 256 threads = 4 waves, wave w owns rows
// [w*32, w*32+32) x all 128 cols. BN == group size (128) and tiles are
// group-aligned, so mean/var/min over the group are exact in-block.
//
// LDS layout XOR-swizzle: logical (row, chunk c of 8 bf16) stored at chunk
// index c ^ (row & 7). Staging keeps LDS dest linear in tid (global_load_lds
// requirement); the swizzle is applied on the GLOBAL source address instead.
// Fragment reads then spread the 16 lanes of a quad across all 8 bank groups
// (2 lanes/bank = conflict-free) instead of 16-way conflicting on one group.
__global__ __launch_bounds__(256) void gemm_gn_min(
    const __bf16* __restrict__ xb, const __bf16* __restrict__ wb,
    const float* __restrict__ bg, const float* __restrict__ gamma,
    const float* __restrict__ beta, float* __restrict__ gmin)
{
    __shared__ __bf16 lA[128 * 64];   // 16 KiB
    __shared__ __bf16 lB[128 * 64];   // 16 KiB

    const int t = threadIdx.x;
    const int m0 = blockIdx.x * 128;
    const int n0 = blockIdx.y * 128;
    const int w = t >> 6;        // wave 0..3
    const int l = t & 63;
    const int quad = l >> 4;
    const int r = l & 15;
    const int r7 = r & 7;

    // staging: thread t's LDS dest is byte offset t*16 within the slab
    // (row rowS, chunk cS); it FETCHES global chunk cS ^ (rowS & 7).
    const int rowS = t >> 3;          // 0..31
    const int cS = t & 7;             // chunk (8 bf16 = 16 B)
    const int cSw = cS ^ (rowS & 7);  // swizzled global chunk

    const __bf16* gA = xb + (size_t)(m0 + rowS) * K_DIM + cSw * 8;
    const __bf16* gB = wb + (size_t)(n0 + rowS) * K_DIM + cSw * 8;
    __bf16* sA = &lA[rowS * 64 + cS * 8];
    __bf16* sB = &lB[rowS * 64 + cS * 8];

    floatx4 acc[2][8];
    #pragma unroll
    for (int i = 0; i < 2; ++i)
        #pragma unroll
        for (int j = 0; j < 8; ++j)
            acc[i][j] = (floatx4){0.f, 0.f, 0.f, 0.f};

    for (int k0 = 0; k0 < K_DIM; k0 += 64) {
        __syncthreads();
        #pragma unroll
        for (int j = 0; j < 4; ++j) {
            // j*32 is a multiple of 8, so (row & 7) — and the swizzle — is unchanged
            g2lds16(gA + k0 + (size_t)(j * 32) * K_DIM, sA + j * 32 * 64);
            g2lds16(gB + k0 + (size_t)(j * 32) * K_DIM, sB + j * 32 * 64);
        }
        __syncthreads();   // drains vmcnt for global_load_lds
        #pragma unroll
        for (int ks = 0; ks < 2; ++ks) {
            const int ca = ((ks * 4 + quad) ^ r7) * 8;  // swizzled chunk offset (elements)
            bf16x8 af[2], bfv[8];
            #pragma unroll
            for (int mt = 0; mt < 2; ++mt)
                af[mt] = *(const bf16x8*)&lA[(w * 32 + mt * 16 + r) * 64 + ca];
            #pragma unroll
            for (int nt = 0; nt < 8; ++nt)
                bfv[nt] = *(const bf16x8*)&lB[(nt * 16 + r) * 64 + ca];
            #pragma unroll
            for (int mt = 0; mt < 2; ++mt)
                #pragma unroll
                for (int nt = 0; nt < 8; ++nt)
                    acc[mt][nt] = __builtin_amdgcn_mfma_f32_16x16x32_bf16(
                        af[mt], bfv[nt], acc[mt][nt], 0, 0, 0);
        }
    }

    // ---- epilogue: + b_gemm, GroupNorm stats over the 128-col group, min ----
    // C/D layout (verified m89/m91): col = lane&15, row = (lane>>4)*4 + reg.
    float bgv[8], gv[8], bv[8];
    #pragma unroll
    for (int nt = 0; nt < 8; ++nt) {
        int c = n0 + nt * 16 + r;
        bgv[nt] = bg[c];
        gv[nt]  = gamma[c];
        bv[nt]  = beta[c];
    }

    #pragma unroll
    for (int mt = 0; mt < 2; ++mt) {
        #pragma unroll
        for (int reg = 0; reg < 4; ++reg) {
            float yv[8];
            float s = 0.f, ss = 0.f;
            #pragma unroll
            for (int nt = 0; nt < 8; ++nt) {
                float y = acc[mt][nt][reg] + bgv[nt];
                yv[nt] = y;
                s += y;
                ss += y * y;
            }
            // reduce across the 16 lanes of this quad (cols nt*16+r cover all 128)
            #pragma unroll
            for (int d = 1; d < 16; d <<= 1) {
                s  += __shfl_xor(s,  d, 64);
                ss += __shfl_xor(ss, d, 64);
            }
            float mean = s * (1.0f / 128.0f);
            float var  = ss * (1.0f / 128.0f) - mean * mean;
            float rstd = rsqrtf(var + EPSV);
            float mn = 1e30f;
            #pragma unroll
            for (int nt = 0; nt < 8; ++nt) {
                float z = (yv[nt] - mean) * rstd * gv[nt] + bv[nt];
                mn = fminf(mn, z);
            }
            #pragma unroll
            for (int d = 1; d < 16; d <<= 1)
                mn = fminf(mn, __shfl_xor(mn, d, 64));
            if (r == 0) {
                int R = m0 + w * 32 + mt * 16 + quad * 4 + reg;
                gmin[(size_t)R * NGROUP + blockIdx.y] = mn;
            }
        }
    }
}

// ---------------- kernel 3: rowmin over groups + broadcast bias ----------------
__global__ __launch_bounds__(256) void finalize(
    const float* __restrict__ gmin, const float* __restrict__ bias,
    float* __restrict__ out)
{
    const int m = blockIdx.x;
    const int t = threadIdx.x;
    float v = gmin[(size_t)m * NGROUP + (t & 31)];
    #pragma unroll
    for (int d = 1; d < 32; d <<= 1)
        v = fminf(v, __shfl_xor(v, d, 64));
    float4* out4 = (float4*)(out + (size_t)m * N_DIM);
    const float4* bias4 = (const float4*)bias;
    for (int i = t; i < N_DIM / 4; i += 256) {
        float4 b = bias4[i];
        out4[i] = make_float4(v + b.x, v + b.y, v + b.z, v + b.w);
    }
}

extern "C" void kernel_launch(void* const* d_in, const int* in_sizes, int n_in,
                              void* d_out, int out_size, void* d_ws, size_t ws_size,
                              hipStream_t stream)
{
    const float* x     = (const float*)d_in[0];
    const float* W     = (const float*)d_in[1];
    const float* bg    = (const float*)d_in[2];
    const float* gamma = (const float*)d_in[3];
    const float* beta  = (const float*)d_in[4];
    const float* bias  = (const float*)d_in[5];
    float* out = (float*)d_out;

    // ws layout: xb (32 MiB bf16) | wb (16 MiB bf16) | gmin (1 MiB fp32) = 49 MiB
    __bf16* xb = (__bf16*)d_ws;
    __bf16* wb = xb + (size_t)M_DIM * K_DIM;
    float* gmin = (float*)(wb + (size_t)N_DIM * K_DIM);

    size_t ntot4 = ((size_t)M_DIM * K_DIM + (size_t)N_DIM * K_DIM) / 4;
    int cvt_blocks = (int)((ntot4 + 255) / 256);
    convert_bf16<<<cvt_blocks, 256, 0, stream>>>(x, W, xb, wb);

    dim3 grid(M_DIM / 128, N_DIM / 128);
    gemm_gn_min<<<grid, 256, 0, stream>>>(xb, wb, bg, gamma, beta, gmin);

    finalize<<<M_DIM, 256, 0, stream>>>(gmin, bias, out);
}

// Round 3
// 378.216 us; speedup vs baseline: 1.1083x; 1.0285x over previous
//
#include <hip/hip_runtime.h>
#include <hip/hip_bf16.h>

#define M_DIM 8192
#define K_DIM 2048
#define N_DIM 4096
#define NGROUP 32
#define EPSV 1e-5f

typedef __bf16 bf16x8 __attribute__((ext_vector_type(8)));
typedef __bf16 bf16x4 __attribute__((ext_vector_type(4)));
typedef float floatx4 __attribute__((ext_vector_type(4)));

__device__ __forceinline__ void g2lds16(const void* g, void* l) {
    __builtin_amdgcn_global_load_lds(
        (__attribute__((address_space(1))) void*)(uintptr_t)g,
        (__attribute__((address_space(3))) void*)(uint32_t)(uintptr_t)l,
        16, 0, 0);
}

// ---------------- kernel 1: fp32 -> bf16 cast of x and W ----------------
__global__ __launch_bounds__(256) void convert_bf16(
    const float* __restrict__ x, const float* __restrict__ w,
    __bf16* __restrict__ xb, __bf16* __restrict__ wb)
{
    const size_t nx = (size_t)M_DIM * K_DIM / 4;
    const size_t nw = (size_t)N_DIM * K_DIM / 4;
    size_t i = (size_t)blockIdx.x * 256 + threadIdx.x;
    if (i < nx) {
        float4 v = ((const float4*)x)[i];
        bf16x4 o = { (__bf16)v.x, (__bf16)v.y, (__bf16)v.z, (__bf16)v.w };
        ((bf16x4*)xb)[i] = o;
    } else if (i < nx + nw) {
        size_t j = i - nx;
        float4 v = ((const float4*)w)[j];
        bf16x4 o = { (__bf16)v.x, (__bf16)v.y, (__bf16)v.z, (__bf16)v.w };
        ((bf16x4*)wb)[j] = o;
    }
}

// ---- kernel 2: bf16 MFMA GEMM (y = x*W^T + b) fused with GroupNorm + group-min ----
// Tile: BM=128, BN=128, BK=64. 128 threads = 2 waves; wave w owns rows
// [w*64, w*64+64) x all 128 cols (4 mt x 8 nt of 16x16x32 MFMA tiles).
// Rationale (R2): per-wave LDS read traffic drops to 12 b128 per 524 kFLOP
// (0.0234 B/FLOP, was 0.039) — the R1/R2 kernel was LDS-read-pipe bound
// (~70% of the 52 TB/s b128 ceiling at 744 TF).
// BN == group size (128) and tiles are group-aligned, so GroupNorm
// mean/var/min are exact in-wave.
//
// LDS XOR-swizzle (R1, verified conflict-free): logical (row, chunk c of
// 8 bf16) stored at chunk c ^ (row & 7); swizzle applied on the GLOBAL
// source address so the global_load_lds dest stays linear in tid.
__global__ __launch_bounds__(128, 2) void gemm_gn_min(
    const __bf16* __restrict__ xb, const __bf16* __restrict__ wb,
    const float* __restrict__ bg, const float* __restrict__ gamma,
    const float* __restrict__ beta, float* __restrict__ gmin)
{
    __shared__ __bf16 lA[128 * 64];   // 16 KiB
    __shared__ __bf16 lB[128 * 64];   // 16 KiB

    const int t = threadIdx.x;
    const int m0 = blockIdx.x * 128;
    const int n0 = blockIdx.y * 128;
    const int w = t >> 6;        // wave 0..1
    const int l = t & 63;
    const int quad = l >> 4;
    const int r = l & 15;
    const int r7 = r & 7;

    // staging: 128 threads; thread t covers LDS bytes t*16 + round*2048.
    // Per round j: row = (t>>3) + j*16, chunk = t&7. (row&7) is round-invariant.
    const int rowS = t >> 3;          // 0..15
    const int cS = t & 7;             // 16 B chunk
    const int cSw = cS ^ (rowS & 7);  // swizzled global chunk

    const __bf16* gA = xb + (size_t)(m0 + rowS) * K_DIM + cSw * 8;
    const __bf16* gB = wb + (size_t)(n0 + rowS) * K_DIM + cSw * 8;
    __bf16* sA = &lA[rowS * 64 + cS * 8];
    __bf16* sB = &lB[rowS * 64 + cS * 8];

    floatx4 acc[4][8];
    #pragma unroll
    for (int i = 0; i < 4; ++i)
        #pragma unroll
        for (int j = 0; j < 8; ++j)
            acc[i][j] = (floatx4){0.f, 0.f, 0.f, 0.f};

    for (int k0 = 0; k0 < K_DIM; k0 += 64) {
        __syncthreads();
        #pragma unroll
        for (int j = 0; j < 8; ++j) {
            // j*16 is a multiple of 8 -> (row & 7) and the swizzle are unchanged
            g2lds16(gA + k0 + (size_t)(j * 16) * K_DIM, sA + j * 16 * 64);
            g2lds16(gB + k0 + (size_t)(j * 16) * K_DIM, sB + j * 16 * 64);
        }
        __syncthreads();   // drains vmcnt for global_load_lds
        #pragma unroll
        for (int ks = 0; ks < 2; ++ks) {
            const int ca = ((ks * 4 + quad) ^ r7) * 8;  // swizzled chunk offset (elements)
            bf16x8 af[4], bfv[8];
            #pragma unroll
            for (int mt = 0; mt < 4; ++mt)
                af[mt] = *(const bf16x8*)&lA[(w * 64 + mt * 16 + r) * 64 + ca];
            #pragma unroll
            for (int nt = 0; nt < 8; ++nt)
                bfv[nt] = *(const bf16x8*)&lB[(nt * 16 + r) * 64 + ca];
            #pragma unroll
            for (int mt = 0; mt < 4; ++mt)
                #pragma unroll
                for (int nt = 0; nt < 8; ++nt)
                    acc[mt][nt] = __builtin_amdgcn_mfma_f32_16x16x32_bf16(
                        af[mt], bfv[nt], acc[mt][nt], 0, 0, 0);
        }
    }

    // ---- epilogue: + b_gemm, GroupNorm stats over the 128-col group, min ----
    // C/D layout (verified m89/m91): col = lane&15, row = (lane>>4)*4 + reg.
    float bgv[8], gv[8], bv[8];
    #pragma unroll
    for (int nt = 0; nt < 8; ++nt) {
        int c = n0 + nt * 16 + r;
        bgv[nt] = bg[c];
        gv[nt]  = gamma[c];
        bv[nt]  = beta[c];
    }

    #pragma unroll
    for (int mt = 0; mt < 4; ++mt) {
        #pragma unroll
        for (int reg = 0; reg < 4; ++reg) {
            float yv[8];
            float s = 0.f, ss = 0.f;
            #pragma unroll
            for (int nt = 0; nt < 8; ++nt) {
                float y = acc[mt][nt][reg] + bgv[nt];
                yv[nt] = y;
                s += y;
                ss += y * y;
            }
            // reduce across the 16 lanes of this quad (cols nt*16+r cover all 128)
            #pragma unroll
            for (int d = 1; d < 16; d <<= 1) {
                s  += __shfl_xor(s,  d, 64);
                ss += __shfl_xor(ss, d, 64);
            }
            float mean = s * (1.0f / 128.0f);
            float var  = ss * (1.0f / 128.0f) - mean * mean;
            float rstd = rsqrtf(var + EPSV);
            float mn = 1e30f;
            #pragma unroll
            for (int nt = 0; nt < 8; ++nt) {
                float z = (yv[nt] - mean) * rstd * gv[nt] + bv[nt];
                mn = fminf(mn, z);
            }
            #pragma unroll
            for (int d = 1; d < 16; d <<= 1)
                mn = fminf(mn, __shfl_xor(mn, d, 64));
            if (r == 0) {
                int R = m0 + w * 64 + mt * 16 + quad * 4 + reg;
                gmin[(size_t)R * NGROUP + blockIdx.y] = mn;
            }
        }
    }
}

// ---------------- kernel 3: rowmin over groups + broadcast bias ----------------
__global__ __launch_bounds__(256) void finalize(
    const float* __restrict__ gmin, const float* __restrict__ bias,
    float* __restrict__ out)
{
    const int m = blockIdx.x;
    const int t = threadIdx.x;
    float v = gmin[(size_t)m * NGROUP + (t & 31)];
    #pragma unroll
    for (int d = 1; d < 32; d <<= 1)
        v = fminf(v, __shfl_xor(v, d, 64));
    float4* out4 = (float4*)(out + (size_t)m * N_DIM);
    const float4* bias4 = (const float4*)bias;
    for (int i = t; i < N_DIM / 4; i += 256) {
        float4 b = bias4[i];
        out4[i] = make_float4(v + b.x, v + b.y, v + b.z, v + b.w);
    }
}

extern "C" void kernel_launch(void* const* d_in, const int* in_sizes, int n_in,
                              void* d_out, int out_size, void* d_ws, size_t ws_size,
                              hipStream_t stream)
{
    const float* x     = (const float*)d_in[0];
    const float* W     = (const float*)d_in[1];
    const float* bg    = (const float*)d_in[2];
    const float* gamma = (const float*)d_in[3];
    const float* beta  = (const float*)d_in[4];
    const float* bias  = (const float*)d_in[5];
    float* out = (float*)d_out;

    // ws layout: xb (32 MiB bf16) | wb (16 MiB bf16) | gmin (1 MiB fp32) = 49 MiB
    __bf16* xb = (__bf16*)d_ws;
    __bf16* wb = xb + (size_t)M_DIM * K_DIM;
    float* gmin = (float*)(wb + (size_t)N_DIM * K_DIM);

    size_t ntot4 = ((size_t)M_DIM * K_DIM + (size_t)N_DIM * K_DIM) / 4;
    int cvt_blocks = (int)((ntot4 + 255) / 256);
    convert_bf16<<<cvt_blocks, 256, 0, stream>>>(x, W, xb, wb);

    dim3 grid(M_DIM / 128, N_DIM / 128);
    gemm_gn_min<<<grid, 128, 0, stream>>>(xb, wb, bg, gamma, beta, gmin);

    finalize<<<M_DIM, 256, 0, stream>>>(gmin, bias, out);
}

// Round 4
// 340.847 us; speedup vs baseline: 1.2298x; 1.1096x over previous
//
#include <hip/hip_runtime.h>
#include <hip/hip_bf16.h>

#define M_DIM 8192
#define K_DIM 2048
#define N_DIM 4096
#define NGROUP 32
#define EPSV 1e-5f

typedef __bf16 bf16x8 __attribute__((ext_vector_type(8)));
typedef __bf16 bf16x4 __attribute__((ext_vector_type(4)));
typedef float floatx4 __attribute__((ext_vector_type(4)));

__device__ __forceinline__ void g2lds16(const void* g, void* l) {
    __builtin_amdgcn_global_load_lds(
        (__attribute__((address_space(1))) void*)(uintptr_t)g,
        (__attribute__((address_space(3))) void*)(uint32_t)(uintptr_t)l,
        16, 0, 0);
}

// ---------------- kernel 1: fp32 -> bf16 cast of x and W ----------------
// Each thread converts 8 floats: two float4 loads -> one 16 B bf16x8 store.
__global__ __launch_bounds__(256) void convert_bf16(
    const float* __restrict__ x, const float* __restrict__ w,
    __bf16* __restrict__ xb, __bf16* __restrict__ wb)
{
    const size_t nx = (size_t)M_DIM * K_DIM / 8;
    const size_t nw = (size_t)N_DIM * K_DIM / 8;
    size_t i = (size_t)blockIdx.x * 256 + threadIdx.x;
    const float4* src;
    bf16x8* dst;
    size_t j;
    if (i < nx) { src = (const float4*)x; dst = (bf16x8*)xb; j = i; }
    else if (i < nx + nw) { src = (const float4*)w; dst = (bf16x8*)wb; j = i - nx; }
    else return;
    float4 a = src[j * 2];
    float4 b = src[j * 2 + 1];
    bf16x8 o = { (__bf16)a.x, (__bf16)a.y, (__bf16)a.z, (__bf16)a.w,
                 (__bf16)b.x, (__bf16)b.y, (__bf16)b.z, (__bf16)b.w };
    dst[j] = o;
}

// ---- kernel 2: bf16 MFMA GEMM (y = x*W^T + b) fused with GroupNorm + group-min ----
// Tile: BM=256, BN=128, BK=64. 256 threads = 4 waves; wave w owns rows
// [w*64, w*64+64) x all 128 cols (4 mt x 8 nt of 16x16x32 MFMA tiles — same
// per-wave register tile as R3).
// R4 rationale: 85 FLOP per staged byte (was 65) cuts block-staging cache
// traffic 2.0 -> 1.5 GiB/dispatch, and 4-wave blocks at 48 KiB LDS give
// 2 blocks/CU = 8 waves/CU (was ~5.3) to overlap the barrier drain.
// BN == group size (128) and tiles are group-aligned, so GroupNorm
// mean/var/min are exact in-wave.
//
// LDS XOR-swizzle (R1, verified conflict-free): logical (row, chunk c of
// 8 bf16) stored at chunk c ^ (row & 7); swizzle applied on the GLOBAL
// source address so the global_load_lds dest stays linear in tid.
__global__ __launch_bounds__(256, 2) void gemm_gn_min(
    const __bf16* __restrict__ xb, const __bf16* __restrict__ wb,
    const float* __restrict__ bg, const float* __restrict__ gamma,
    const float* __restrict__ beta, float* __restrict__ gmin)
{
    __shared__ __bf16 lA[256 * 64];   // 32 KiB
    __shared__ __bf16 lB[128 * 64];   // 16 KiB

    const int t = threadIdx.x;
    const int m0 = blockIdx.x * 256;
    const int n0 = blockIdx.y * 128;
    const int w = t >> 6;        // wave 0..3
    const int l = t & 63;
    const int quad = l >> 4;
    const int r = l & 15;
    const int r7 = r & 7;

    // staging: 256 threads; per round j thread t covers (row = (t>>3)+j*32,
    // chunk = t&7). j*32 is a multiple of 8 -> (row & 7) and swizzle invariant.
    const int rowS = t >> 3;          // 0..31
    const int cS = t & 7;             // 16 B chunk
    const int cSw = cS ^ (rowS & 7);  // swizzled global chunk

    const __bf16* gA = xb + (size_t)(m0 + rowS) * K_DIM + cSw * 8;
    const __bf16* gB = wb + (size_t)(n0 + rowS) * K_DIM + cSw * 8;
    __bf16* sA = &lA[rowS * 64 + cS * 8];
    __bf16* sB = &lB[rowS * 64 + cS * 8];

    floatx4 acc[4][8];
    #pragma unroll
    for (int i = 0; i < 4; ++i)
        #pragma unroll
        for (int j = 0; j < 8; ++j)
            acc[i][j] = (floatx4){0.f, 0.f, 0.f, 0.f};

    for (int k0 = 0; k0 < K_DIM; k0 += 64) {
        __syncthreads();
        #pragma unroll
        for (int j = 0; j < 8; ++j)   // A: 256 rows in 8 rounds of 32
            g2lds16(gA + k0 + (size_t)(j * 32) * K_DIM, sA + j * 32 * 64);
        #pragma unroll
        for (int j = 0; j < 4; ++j)   // B: 128 rows in 4 rounds of 32
            g2lds16(gB + k0 + (size_t)(j * 32) * K_DIM, sB + j * 32 * 64);
        __syncthreads();   // drains vmcnt for global_load_lds
        #pragma unroll
        for (int ks = 0; ks < 2; ++ks) {
            const int ca = ((ks * 4 + quad) ^ r7) * 8;  // swizzled chunk offset (elements)
            bf16x8 af[4], bfv[8];
            #pragma unroll
            for (int mt = 0; mt < 4; ++mt)
                af[mt] = *(const bf16x8*)&lA[(w * 64 + mt * 16 + r) * 64 + ca];
            #pragma unroll
            for (int nt = 0; nt < 8; ++nt)
                bfv[nt] = *(const bf16x8*)&lB[(nt * 16 + r) * 64 + ca];
            #pragma unroll
            for (int mt = 0; mt < 4; ++mt)
                #pragma unroll
                for (int nt = 0; nt < 8; ++nt)
                    acc[mt][nt] = __builtin_amdgcn_mfma_f32_16x16x32_bf16(
                        af[mt], bfv[nt], acc[mt][nt], 0, 0, 0);
        }
    }

    // ---- epilogue: + b_gemm, GroupNorm stats over the 128-col group, min ----
    // C/D layout (verified m89/m91): col = lane&15, row = (lane>>4)*4 + reg.
    float bgv[8], gv[8], bv[8];
    #pragma unroll
    for (int nt = 0; nt < 8; ++nt) {
        int c = n0 + nt * 16 + r;
        bgv[nt] = bg[c];
        gv[nt]  = gamma[c];
        bv[nt]  = beta[c];
    }

    #pragma unroll
    for (int mt = 0; mt < 4; ++mt) {
        #pragma unroll
        for (int reg = 0; reg < 4; ++reg) {
            float yv[8];
            float s = 0.f, ss = 0.f;
            #pragma unroll
            for (int nt = 0; nt < 8; ++nt) {
                float y = acc[mt][nt][reg] + bgv[nt];
                yv[nt] = y;
                s += y;
                ss += y * y;
            }
            // reduce across the 16 lanes of this quad (cols nt*16+r cover all 128)
            #pragma unroll
            for (int d = 1; d < 16; d <<= 1) {
                s  += __shfl_xor(s,  d, 64);
                ss += __shfl_xor(ss, d, 64);
            }
            float mean = s * (1.0f / 128.0f);
            float var  = ss * (1.0f / 128.0f) - mean * mean;
            float rstd = rsqrtf(var + EPSV);
            float mn = 1e30f;
            #pragma unroll
            for (int nt = 0; nt < 8; ++nt) {
                float z = (yv[nt] - mean) * rstd * gv[nt] + bv[nt];
                mn = fminf(mn, z);
            }
            #pragma unroll
            for (int d = 1; d < 16; d <<= 1)
                mn = fminf(mn, __shfl_xor(mn, d, 64));
            if (r == 0) {
                int R = m0 + w * 64 + mt * 16 + quad * 4 + reg;
                gmin[(size_t)R * NGROUP + blockIdx.y] = mn;
            }
        }
    }
}

// ---------------- kernel 3: rowmin over groups + broadcast bias ----------------
__global__ __launch_bounds__(256) void finalize(
    const float* __restrict__ gmin, const float* __restrict__ bias,
    float* __restrict__ out)
{
    const int m = blockIdx.x;
    const int t = threadIdx.x;
    float v = gmin[(size_t)m * NGROUP + (t & 31)];
    #pragma unroll
    for (int d = 1; d < 32; d <<= 1)
        v = fminf(v, __shfl_xor(v, d, 64));
    float4* out4 = (float4*)(out + (size_t)m * N_DIM);
    const float4* bias4 = (const float4*)bias;
    for (int i = t; i < N_DIM / 4; i += 256) {
        float4 b = bias4[i];
        out4[i] = make_float4(v + b.x, v + b.y, v + b.z, v + b.w);
    }
}

extern "C" void kernel_launch(void* const* d_in, const int* in_sizes, int n_in,
                              void* d_out, int out_size, void* d_ws, size_t ws_size,
                              hipStream_t stream)
{
    const float* x     = (const float*)d_in[0];
    const float* W     = (const float*)d_in[1];
    const float* bg    = (const float*)d_in[2];
    const float* gamma = (const float*)d_in[3];
    const float* beta  = (const float*)d_in[4];
    const float* bias  = (const float*)d_in[5];
    float* out = (float*)d_out;

    // ws layout: xb (32 MiB bf16) | wb (16 MiB bf16) | gmin (1 MiB fp32) = 49 MiB
    __bf16* xb = (__bf16*)d_ws;
    __bf16* wb = xb + (size_t)M_DIM * K_DIM;
    float* gmin = (float*)(wb + (size_t)N_DIM * K_DIM);

    size_t ntot8 = ((size_t)M_DIM * K_DIM + (size_t)N_DIM * K_DIM) / 8;
    int cvt_blocks = (int)((ntot8 + 255) / 256);
    convert_bf16<<<cvt_blocks, 256, 0, stream>>>(x, W, xb, wb);

    dim3 grid(M_DIM / 256, N_DIM / 128);
    gemm_gn_min<<<grid, 256, 0, stream>>>(xb, wb, bg, gamma, beta, gmin);

    finalize<<<M_DIM, 256, 0, stream>>>(gmin, bias, out);
}